// Round 8
// baseline (155.356 us; speedup 1.0000x reference)
//
#include <hip/hip_runtime.h>
#include <math.h>

// Problem constants (from reference): B=32, Q=4096, G=32, C=128
#define NB   32
#define BQ   4096
#define GMAX 32
#define NC   128
#define BS   512            // solver threads per block
#define CPT  (BQ / BS)      // 8 contiguous columns per thread: j = tid*8 + k
#define NWAVE (BS / 64)     // 8 waves

#define BBS  256            // build block size (thread per q)

// ---------------- Kernel 1: streaming cost build (no LDS, no barriers) ----
// cost[b][i][q] = -sem[b,q,lab_i] - 0.5*obj[b,q] + cent[b,q,i] - 2*giou[b,q,i]
// exact f32 per-op rounding in reference order. Thread = one q; ~49
// independent loads in flight per thread (MLP-bound fix for the 42us build).
__launch_bounds__(BBS)
__global__ void build_cost_kernel(const float* __restrict__ sem,
                                  const float* __restrict__ objp,
                                  const float* __restrict__ cent,
                                  const float* __restrict__ giou,
                                  const int*   __restrict__ labels,
                                  const int*   __restrict__ nact,
                                  float* __restrict__ cost)      // [B][G][Q]
{
    const int b = blockIdx.x >> 4;                       // 16 blocks per batch
    const int q = ((blockIdx.x & 15) << 8) + threadIdx.x;
    const int ng = nact[b];

    // labels are block-uniform -> scalar registers
    int lab[GMAX];
#pragma unroll
    for (int i = 0; i < GMAX; i++) lab[i] = labels[b * GMAX + i];

    const float*  semrow = sem + ((size_t)b * BQ + q) * NC;
    const float4* cq = (const float4*)(cent + ((size_t)b * BQ + q) * GMAX);
    const float4* gq = (const float4*)(giou + ((size_t)b * BQ + q) * GMAX);

    // issue everything independently: 8+8 float4 + 32 gathers + 1 scalar
    float4 cr[8], gr[8];
#pragma unroll
    for (int x = 0; x < 8; x++) { cr[x] = cq[x]; gr[x] = gq[x]; }
    float sv[GMAX];
#pragma unroll
    for (int i = 0; i < GMAX; i++) sv[i] = semrow[lab[i]];
    const float ho = __fmul_rn(0.5f, objp[b * BQ + q]);

    const float* crf = (const float*)cr;
    const float* grf = (const float*)gr;
    float* cb = cost + (size_t)b * GMAX * BQ + q;

#pragma unroll
    for (int i = 0; i < GMAX; i++) {
        float c = __fsub_rn(__fadd_rn(__fsub_rn(-sv[i], ho), crf[i]),
                            __fmul_rn(2.0f, grf[i]));
        if (i < ng) cb[(size_t)i * BQ] = c;   // coalesced across lanes
    }
}

// ---------------- Kernel 2: JV Hungarian solver with greedy warm start ----
// One block per batch. Dual-feasible warm start: u[i] = min_j cost[i][j],
// v = 0; greedy-assign each row to its (first-index) argmin column if free.
// Colliding rows run the exact f64 Dijkstra augmentation (first-index
// tie-break). Complementary slackness holds throughout => optimal matching;
// continuous random costs => unique optimum => matches the reference.
__launch_bounds__(BS, 1)
__global__ void matcher_kernel(const float* __restrict__ cost,   // [B][G][Q]
                               const int*   __restrict__ nact,   // [B]
                               float* __restrict__ out)          // [2*B*Q]
{
    const int b    = blockIdx.x;
    const int tid  = threadIdx.x;
    const int m    = BQ;
    const int wave = tid >> 6;
    const int lane = tid & 63;

    __shared__ __align__(16) short p_lds[BQ + 8];       // matched row per col
    __shared__ __align__(16) unsigned short way_lds[BQ];
    __shared__ double u_lds[GMAX];
    __shared__ double   redv[2][NWAVE];
    __shared__ unsigned redpk[2][NWAVE];
    __shared__ int    step_i0[GMAX + 2];
    __shared__ double step_D[GMAX + 2];
    __shared__ float  rmin_v[GMAX];
    __shared__ int    rmin_j[GMAX];
    __shared__ int    unmatched[GMAX];
    __shared__ int    s_nunm;

    for (int k = tid; k < BQ + 8; k += BS) p_lds[k] = -1;
    const int ng = nact[b];
    const float* cb = cost + (size_t)b * GMAX * BQ;
    __syncthreads();

    // ---- Pass 1: per-row (min, first-argmin), wave-parallel, no barriers ----
    for (int r = wave; r < ng; r += NWAVE) {
        const float4* row4 = (const float4*)(cb + (size_t)r * BQ);
        float bv = INFINITY; int bj = 0;
#pragma unroll
        for (int it = 0; it < 16; it++) {
            float4 vv = row4[lane + 64 * it];
            int j = (lane + 64 * it) * 4;       // ascending within lane
            if (vv.x < bv) { bv = vv.x; bj = j; }
            if (vv.y < bv) { bv = vv.y; bj = j + 1; }
            if (vv.z < bv) { bv = vv.z; bj = j + 2; }
            if (vv.w < bv) { bv = vv.w; bj = j + 3; }
        }
#pragma unroll
        for (int off = 32; off >= 1; off >>= 1) {
            float ov = __shfl_down(bv, off, 64);
            int   oj = __shfl_down(bj, off, 64);
            if (ov < bv || (ov == bv && oj < bj)) { bv = ov; bj = oj; }
        }
        if (lane == 0) { rmin_v[r] = bv; rmin_j[r] = bj; }
    }
    __syncthreads();

    // ---- duals + greedy assignment (thread 0, <=32 iters) ----
    if (tid < ng) u_lds[tid] = (double)rmin_v[tid];
    if (tid == 0) {
        int nu = 0;
        for (int i = 0; i < ng; i++) {
            int j = rmin_j[i];
            if (p_lds[j] < 0) p_lds[j] = (short)i;
            else unmatched[nu++] = i;           // ascending row order
        }
        s_nunm = nu;
    }
    __syncthreads();
    const int nunm = s_nunm;

    const double INF = (double)INFINITY;
    const int jbase = tid * CPT;
    const float4* cb4 = (const float4*)cb;

    double v_reg[CPT], minv[CPT], enterD[CPT];
    int way_reg[CPT], p_reg[CPT];
#pragma unroll
    for (int k = 0; k < CPT; k++) { v_reg[k] = 0.0; way_reg[k] = m; enterD[k] = 0.0; }

    for (int t = 0; t < nunm; t++) {
        const int ri = unmatched[t];

        // refresh p_reg (one ds_read_b128; p constant during the phase)
        int4 pv = ((const int4*)p_lds)[tid];
        p_reg[0] = (int)(short)(pv.x & 0xFFFF); p_reg[1] = pv.x >> 16;
        p_reg[2] = (int)(short)(pv.y & 0xFFFF); p_reg[3] = pv.y >> 16;
        p_reg[4] = (int)(short)(pv.z & 0xFFFF); p_reg[5] = pv.z >> 16;
        p_reg[6] = (int)(short)(pv.w & 0xFFFF); p_reg[7] = pv.w >> 16;

        // initial row load (row ri) + its u
        const float4* r4 = cb4 + (size_t)ri * (BQ / 4) + tid * 2;
        float4 c0 = r4[0];
        float4 c1 = r4[1];
        double ui0 = u_lds[ri];

#pragma unroll
        for (int k = 0; k < CPT; k++) minv[k] = INF;
        unsigned used_mask = 0;
        int i0 = ri, j0 = m, ns = 0, buf = 0, jfin;
        double D = 0.0;

        while (true) {
            float cf[CPT] = {c0.x, c0.y, c0.z, c0.w, c1.x, c1.y, c1.z, c1.w};

            // relax + per-thread lexicographic argmin (ascending k == asc. j)
            double bestv = INF;
            unsigned bestpk = ((unsigned)m << 8);
#pragma unroll
            for (int k = 0; k < CPT; k++) {
                bool un = !((used_mask >> k) & 1u);
                double cur = ((double)cf[k] - ui0) - v_reg[k];
                bool better = un && (cur < minv[k]);
                if (better) { minv[k] = cur; way_reg[k] = j0; }
                double mv = un ? minv[k] : INF;
                if (mv < bestv) {
                    bestv = mv;
                    bestpk = (((unsigned)(jbase + k)) << 8) | (unsigned)(p_reg[k] + 1);
                }
            }

            // wave-level lexicographic (val, packed-j) min
#pragma unroll
            for (int off = 32; off >= 1; off >>= 1) {
                double   ov  = __shfl_down(bestv, off, 64);
                unsigned opk = __shfl_down(bestpk, off, 64);
                if (ov < bestv || (ov == bestv && opk < bestpk)) { bestv = ov; bestpk = opk; }
            }
            if (lane == 0) { redv[buf][wave] = bestv; redpk[buf][wave] = bestpk; }
            __syncthreads();                               // the ONLY barrier

            // redundant final reduce on every thread (LDS broadcast reads)
            double delta = redv[buf][0]; unsigned pk = redpk[buf][0];
#pragma unroll
            for (int w = 1; w < NWAVE; w++) {
                double ov = redv[buf][w]; unsigned opk = redpk[buf][w];
                if (ov < delta || (ov == delta && opk < pk)) { delta = ov; pk = opk; }
            }
            const int j1 = (int)(pk >> 8);
            const int pi = (int)(pk & 0xFFu) - 1;

            if (tid == 0) { step_i0[ns] = i0; step_D[ns] = D; }
            D += delta;
            ns++;

            if (pi < 0) { jfin = j1; break; }

            // prefetch next row + its u under the update shadow
            const float4* n4 = cb4 + (size_t)pi * (BQ / 4) + tid * 2;
            c0 = n4[0];
            c1 = n4[1];
            ui0 = u_lds[pi];

#pragma unroll
            for (int k = 0; k < CPT; k++)
                if (!((used_mask >> k) & 1u)) minv[k] -= delta;

            unsigned kk = (unsigned)(j1 - jbase);
            if (kk < CPT) { used_mask |= (1u << kk); enterD[kk] = D; }

            i0 = pi; j0 = j1; buf ^= 1;
        }

        // closed-form dual updates (same f64 values as per-step updates)
#pragma unroll
        for (int k = 0; k < CPT; k++)
            if ((used_mask >> k) & 1u) v_reg[k] -= (D - enterD[k]);

        // dump way_reg as one packed 16B LDS write
        int4 wv;
        wv.x = (way_reg[0] & 0xFFFF) | (way_reg[1] << 16);
        wv.y = (way_reg[2] & 0xFFFF) | (way_reg[3] << 16);
        wv.z = (way_reg[4] & 0xFFFF) | (way_reg[5] << 16);
        wv.w = (way_reg[6] & 0xFFFF) | (way_reg[7] << 16);
        ((int4*)way_lds)[tid] = wv;

        __syncthreads();   // way/step logs visible to all
        if (tid < ns) u_lds[step_i0[tid]] += D - step_D[tid];  // distinct rows
        if (tid == 0) {
            int jc = jfin;
            while (jc != m) {
                int jp = (int)way_lds[jc];
                p_lds[jc] = (jp == m) ? (short)ri : p_lds[jp];
                jc = jp;
            }
        }
        __syncthreads();
    }

    // ---- write outputs: [per_prop (B*Q), mask (B*Q)] as float ----
#pragma unroll
    for (int k = 0; k < CPT; k++) {
        int j = jbase + k;
        short pj = p_lds[j];
        out[(size_t)b * BQ + j] = (pj >= 0) ? (float)pj : 0.0f;
        out[(size_t)NB * BQ + (size_t)b * BQ + j] = (pj >= 0) ? 1.0f : 0.0f;
    }
}

extern "C" void kernel_launch(void* const* d_in, const int* in_sizes, int n_in,
                              void* d_out, int out_size, void* d_ws, size_t ws_size,
                              hipStream_t stream) {
    const float* sem    = (const float*)d_in[0];  // [B,Q,C]
    const float* objp   = (const float*)d_in[1];  // [B,Q]
    const float* cent   = (const float*)d_in[2];  // [B,Q,G]
    const float* giou   = (const float*)d_in[3];  // [B,Q,G]
    const int*   labels = (const int*)d_in[4];    // [B,G]
    const int*   nact   = (const int*)d_in[5];    // [B]
    float* out  = (float*)d_out;                  // [2*B*Q]
    float* cost = (float*)d_ws;                   // [B][G][Q] = 16 MB

    build_cost_kernel<<<NB * 16, BBS, 0, stream>>>(sem, objp, cent, giou,
                                                   labels, nact, cost);
    matcher_kernel<<<NB, BS, 0, stream>>>(cost, nact, out);
}

// Round 9
// 145.972 us; speedup vs baseline: 1.0643x; 1.0643x over previous
//
#include <hip/hip_runtime.h>
#include <math.h>

// Problem constants (from reference): B=32, Q=4096, G=32, C=128
#define NB   32
#define BQ   4096
#define GMAX 32
#define NC   128
#define BS   512            // solver threads per block
#define CPT  (BQ / BS)      // 8 contiguous columns per thread: j = tid*8 + k
#define NWAVE (BS / 64)     // 8 waves
#define NT64 (BQ / 64)      // 64 q-tiles of 64 per row

// ---------------- Kernel 1: wide streaming cost build + rowmin partials ----
// cost[b][i][q] = -sem[b,q,lab_i] - 0.5*obj[b,q] + cent[b,q,i] - 2*giou[b,q,i]
// exact f32 per-op rounding in reference order. Thread = (q, quad of 8 rows);
// 8192 waves total so per-CU MLP saturates the fetch pipe. Each wave also
// emits per-(row, 64q-tile) (min, first-argmin) partials (lanes = consecutive
// q => first-index tie-break preserved).
__launch_bounds__(256, 6)
__global__ void build_cost_kernel(const float* __restrict__ sem,
                                  const float* __restrict__ objp,
                                  const float* __restrict__ cent,
                                  const float* __restrict__ giou,
                                  const int*   __restrict__ labels,
                                  const int*   __restrict__ nact,
                                  float* __restrict__ cost,      // [B][G][Q]
                                  float2* __restrict__ rowpart)  // [B][G][NT64]
{
    const int blk  = blockIdx.x;            // 0 .. NB*NT64-1
    const int b    = blk >> 6;
    const int qt   = blk & 63;              // 64-q tile index
    const int lane = threadIdx.x & 63;
    const int quad = threadIdx.x >> 6;      // 0..3: rows 8*quad .. 8*quad+7
    const int q    = (qt << 6) + lane;
    const int r0   = quad << 3;
    const int ng   = nact[b];

    if (r0 >= ng) return;                   // whole wave uniform-exits

    // 8 labels for this quad (wave-uniform addresses -> scalarizable)
    int lab[8];
#pragma unroll
    for (int k = 0; k < 8; k++) lab[k] = labels[b * GMAX + r0 + k];

    const float*  semrow = sem + ((size_t)b * BQ + q) * NC;
    const float4* cq = (const float4*)(cent + ((size_t)b * BQ + q) * GMAX) + (r0 >> 2);
    const float4* gq = (const float4*)(giou + ((size_t)b * BQ + q) * GMAX) + (r0 >> 2);

    // independent loads: 2+2 float4 + 8 gathers + 1 scalar
    float4 cr[2], gr[2];
    cr[0] = cq[0]; cr[1] = cq[1];
    gr[0] = gq[0]; gr[1] = gq[1];
    float sv[8];
#pragma unroll
    for (int k = 0; k < 8; k++) sv[k] = semrow[lab[k]];
    const float ho = __fmul_rn(0.5f, objp[b * BQ + q]);

    const float* crf = (const float*)cr;
    const float* grf = (const float*)gr;
    float* cb = cost + ((size_t)b * GMAX + r0) * BQ + q;

#pragma unroll
    for (int k = 0; k < 8; k++) {
        const int i = r0 + k;
        if (i < ng) {                       // wave-uniform (ng, r0, k uniform)
            float c = __fsub_rn(__fadd_rn(__fsub_rn(-sv[k], ho), crf[k]),
                                __fmul_rn(2.0f, grf[k]));
            cb[(size_t)k * BQ] = c;         // 256B coalesced per wave

            // width-64 lexicographic (val, q) min -> per-tile partial
            float bv = c; int bj = q;
#pragma unroll
            for (int off = 32; off >= 1; off >>= 1) {
                float ov = __shfl_down(bv, off, 64);
                int   oj = __shfl_down(bj, off, 64);
                if (ov < bv || (ov == bv && oj < bj)) { bv = ov; bj = oj; }
            }
            if (lane == 0)
                rowpart[((size_t)b * GMAX + i) * NT64 + qt] =
                    make_float2(bv, __int_as_float(bj));
        }
    }
}

// ---------------- Kernel 2: JV Hungarian solver with greedy warm start ----
// One block per batch. Dual-feasible warm start: u[i] = min_j cost[i][j],
// v = 0; greedy-assign each row to its (first-index) argmin column if free.
// Colliding rows run the exact f64 Dijkstra augmentation (first-index
// tie-break). Complementary slackness holds throughout => optimal matching;
// continuous random costs => unique optimum => matches the reference.
__launch_bounds__(BS, 1)
__global__ void matcher_kernel(const float*  __restrict__ cost,     // [B][G][Q]
                               const float2* __restrict__ rowpart,  // [B][G][NT64]
                               const int*    __restrict__ nact,     // [B]
                               float* __restrict__ out)             // [2*B*Q]
{
    const int b    = blockIdx.x;
    const int tid  = threadIdx.x;
    const int m    = BQ;
    const int wave = tid >> 6;
    const int lane = tid & 63;

    __shared__ __align__(16) short p_lds[BQ + 8];       // matched row per col
    __shared__ __align__(16) unsigned short way_lds[BQ];
    __shared__ double u_lds[GMAX];
    __shared__ double   redv[2][NWAVE];
    __shared__ unsigned redpk[2][NWAVE];
    __shared__ int    step_i0[GMAX + 2];
    __shared__ double step_D[GMAX + 2];
    __shared__ float  rmin_v[GMAX];
    __shared__ int    rmin_j[GMAX];
    __shared__ int    unmatched[GMAX];
    __shared__ int    s_nunm;

    for (int k = tid; k < BQ + 8; k += BS) p_lds[k] = -1;
    const int ng = nact[b];
    const float* cb = cost + (size_t)b * GMAX * BQ;
    __syncthreads();

    // ---- Pass 1: per-row (min, first-argmin) from build partials ----
    for (int r = wave; r < ng; r += NWAVE) {
        float2 pp = (rowpart + ((size_t)b * GMAX + r) * NT64)[lane]; // tile=lane
        float bv = pp.x; int bj = __float_as_int(pp.y);
#pragma unroll
        for (int off = 32; off >= 1; off >>= 1) {
            float ov = __shfl_down(bv, off, 64);
            int   oj = __shfl_down(bj, off, 64);
            if (ov < bv || (ov == bv && oj < bj)) { bv = ov; bj = oj; }
        }
        if (lane == 0) { rmin_v[r] = bv; rmin_j[r] = bj; }
    }
    __syncthreads();

    // ---- duals + greedy assignment (thread 0, <=32 iters) ----
    if (tid < ng) u_lds[tid] = (double)rmin_v[tid];
    if (tid == 0) {
        int nu = 0;
        for (int i = 0; i < ng; i++) {
            int j = rmin_j[i];
            if (p_lds[j] < 0) p_lds[j] = (short)i;
            else unmatched[nu++] = i;           // ascending row order
        }
        s_nunm = nu;
    }
    __syncthreads();
    const int nunm = s_nunm;

    const double INF = (double)INFINITY;
    const int jbase = tid * CPT;
    const float4* cb4 = (const float4*)cb;

    double v_reg[CPT], minv[CPT], enterD[CPT];
    int way_reg[CPT], p_reg[CPT];
#pragma unroll
    for (int k = 0; k < CPT; k++) { v_reg[k] = 0.0; way_reg[k] = m; enterD[k] = 0.0; }

    for (int t = 0; t < nunm; t++) {
        const int ri = unmatched[t];

        // refresh p_reg (one ds_read_b128; p constant during the phase)
        int4 pv = ((const int4*)p_lds)[tid];
        p_reg[0] = (int)(short)(pv.x & 0xFFFF); p_reg[1] = pv.x >> 16;
        p_reg[2] = (int)(short)(pv.y & 0xFFFF); p_reg[3] = pv.y >> 16;
        p_reg[4] = (int)(short)(pv.z & 0xFFFF); p_reg[5] = pv.z >> 16;
        p_reg[6] = (int)(short)(pv.w & 0xFFFF); p_reg[7] = pv.w >> 16;

        // initial row load (row ri) + its u
        const float4* r4 = cb4 + (size_t)ri * (BQ / 4) + tid * 2;
        float4 c0 = r4[0];
        float4 c1 = r4[1];
        double ui0 = u_lds[ri];

#pragma unroll
        for (int k = 0; k < CPT; k++) minv[k] = INF;
        unsigned used_mask = 0;
        int i0 = ri, j0 = m, ns = 0, buf = 0, jfin;
        double D = 0.0;

        while (true) {
            float cf[CPT] = {c0.x, c0.y, c0.z, c0.w, c1.x, c1.y, c1.z, c1.w};

            // relax + per-thread lexicographic argmin (ascending k == asc. j)
            double bestv = INF;
            unsigned bestpk = ((unsigned)m << 8);
#pragma unroll
            for (int k = 0; k < CPT; k++) {
                bool un = !((used_mask >> k) & 1u);
                double cur = ((double)cf[k] - ui0) - v_reg[k];
                bool better = un && (cur < minv[k]);
                if (better) { minv[k] = cur; way_reg[k] = j0; }
                double mv = un ? minv[k] : INF;
                if (mv < bestv) {
                    bestv = mv;
                    bestpk = (((unsigned)(jbase + k)) << 8) | (unsigned)(p_reg[k] + 1);
                }
            }

            // wave-level lexicographic (val, packed-j) min
#pragma unroll
            for (int off = 32; off >= 1; off >>= 1) {
                double   ov  = __shfl_down(bestv, off, 64);
                unsigned opk = __shfl_down(bestpk, off, 64);
                if (ov < bestv || (ov == bestv && opk < bestpk)) { bestv = ov; bestpk = opk; }
            }
            if (lane == 0) { redv[buf][wave] = bestv; redpk[buf][wave] = bestpk; }
            __syncthreads();                               // the ONLY barrier

            // redundant final reduce on every thread (LDS broadcast reads)
            double delta = redv[buf][0]; unsigned pk = redpk[buf][0];
#pragma unroll
            for (int w = 1; w < NWAVE; w++) {
                double ov = redv[buf][w]; unsigned opk = redpk[buf][w];
                if (ov < delta || (ov == delta && opk < pk)) { delta = ov; pk = opk; }
            }
            const int j1 = (int)(pk >> 8);
            const int pi = (int)(pk & 0xFFu) - 1;

            if (tid == 0) { step_i0[ns] = i0; step_D[ns] = D; }
            D += delta;
            ns++;

            if (pi < 0) { jfin = j1; break; }

            // prefetch next row + its u under the update shadow
            const float4* n4 = cb4 + (size_t)pi * (BQ / 4) + tid * 2;
            c0 = n4[0];
            c1 = n4[1];
            ui0 = u_lds[pi];

#pragma unroll
            for (int k = 0; k < CPT; k++)
                if (!((used_mask >> k) & 1u)) minv[k] -= delta;

            unsigned kk = (unsigned)(j1 - jbase);
            if (kk < CPT) { used_mask |= (1u << kk); enterD[kk] = D; }

            i0 = pi; j0 = j1; buf ^= 1;
        }

        // closed-form dual updates (same f64 values as per-step updates)
#pragma unroll
        for (int k = 0; k < CPT; k++)
            if ((used_mask >> k) & 1u) v_reg[k] -= (D - enterD[k]);

        // dump way_reg as one packed 16B LDS write
        int4 wv;
        wv.x = (way_reg[0] & 0xFFFF) | (way_reg[1] << 16);
        wv.y = (way_reg[2] & 0xFFFF) | (way_reg[3] << 16);
        wv.z = (way_reg[4] & 0xFFFF) | (way_reg[5] << 16);
        wv.w = (way_reg[6] & 0xFFFF) | (way_reg[7] << 16);
        ((int4*)way_lds)[tid] = wv;

        __syncthreads();   // way/step logs visible to all
        if (tid < ns) u_lds[step_i0[tid]] += D - step_D[tid];  // distinct rows
        if (tid == 0) {
            int jc = jfin;
            while (jc != m) {
                int jp = (int)way_lds[jc];
                p_lds[jc] = (jp == m) ? (short)ri : p_lds[jp];
                jc = jp;
            }
        }
        __syncthreads();
    }

    // ---- write outputs: [per_prop (B*Q), mask (B*Q)] as float ----
#pragma unroll
    for (int k = 0; k < CPT; k++) {
        int j = jbase + k;
        short pj = p_lds[j];
        out[(size_t)b * BQ + j] = (pj >= 0) ? (float)pj : 0.0f;
        out[(size_t)NB * BQ + (size_t)b * BQ + j] = (pj >= 0) ? 1.0f : 0.0f;
    }
}

extern "C" void kernel_launch(void* const* d_in, const int* in_sizes, int n_in,
                              void* d_out, int out_size, void* d_ws, size_t ws_size,
                              hipStream_t stream) {
    const float* sem    = (const float*)d_in[0];  // [B,Q,C]
    const float* objp   = (const float*)d_in[1];  // [B,Q]
    const float* cent   = (const float*)d_in[2];  // [B,Q,G]
    const float* giou   = (const float*)d_in[3];  // [B,Q,G]
    const int*   labels = (const int*)d_in[4];    // [B,G]
    const int*   nact   = (const int*)d_in[5];    // [B]
    float* out  = (float*)d_out;                  // [2*B*Q]
    float*  cost    = (float*)d_ws;                                     // 16 MB
    float2* rowpart = (float2*)((char*)d_ws + (size_t)16 * 1024 * 1024); // 512 KB

    build_cost_kernel<<<NB * NT64, 256, 0, stream>>>(sem, objp, cent, giou,
                                                     labels, nact, cost, rowpart);
    matcher_kernel<<<NB, BS, 0, stream>>>(cost, rowpart, nact, out);
}